// Round 11
// baseline (71.088 us; speedup 1.0000x reference)
//
#include <hip/hip_runtime.h>
#include <math.h>

#define BB 4
#define TT 4096
#define CC 1024
#define HH 64
#define MM (BB*TT)

typedef __attribute__((ext_vector_type(8))) short  short8;
typedef __attribute__((ext_vector_type(4))) short  short4v;
typedef __attribute__((ext_vector_type(4))) float  f32x4;

static __device__ __forceinline__ unsigned short f2bf(float f) {
    union { float f; unsigned u; } v; v.f = f;
    unsigned r = v.u + 0x7FFF + ((v.u >> 16) & 1);
    return (unsigned short)(r >> 16);
}

// ---------------- Kernel 0a: W -> W^T bf16 (tiny, unchanged) ---------------
__global__ __launch_bounds__(256) void convw_kernel(
        const float* __restrict__ Wq, const float* __restrict__ Wk,
        const float* __restrict__ Wv, unsigned short* __restrict__ wtb) {
    __shared__ unsigned short sW[64][66];
    const int m    = blockIdx.x >> 4;
    const int cblk = blockIdx.x & 15;
    const float* W = (m == 0) ? Wq : (m == 1) ? Wk : Wv;
    const int lane = threadIdx.x & 63;
    const int w    = threadIdx.x >> 6;
    #pragma unroll
    for (int rep = 0; rep < 16; ++rep) {
        const int cl = w * 16 + rep;
        sW[cl][lane] = f2bf(W[(size_t)(cblk * 64 + cl) * HH + lane]);
    }
    __syncthreads();
    #pragma unroll
    for (int rep = 0; rep < 16; ++rep) {
        const int h2 = w * 16 + rep;
        wtb[(size_t)(m * 64 + h2) * CC + cblk * 64 + lane] = sW[lane][h2];
    }
}

// ---------------- Kernel 0b: x -> bf16, pure stream (r2-proven 5.3 TB/s) ---
__global__ __launch_bounds__(256) void xconv_kernel(
        const float* __restrict__ x, unsigned short* __restrict__ xb) {
    const size_t i = ((size_t)blockIdx.x * 256 + threadIdx.x) * 8;
    float4 a = *reinterpret_cast<const float4*>(&x[i]);
    float4 b = *reinterpret_cast<const float4*>(&x[i + 4]);
    short8 o;
    o[0] = (short)f2bf(a.x); o[1] = (short)f2bf(a.y);
    o[2] = (short)f2bf(a.z); o[3] = (short)f2bf(a.w);
    o[4] = (short)f2bf(b.x); o[5] = (short)f2bf(b.y);
    o[6] = (short)f2bf(b.z); o[7] = (short)f2bf(b.w);
    *reinterpret_cast<short8*>(&xb[i]) = o;
}

// ---------------- Kernel 1: zero-barrier register-dataflow MFMA GEMM ------
// Hypothesis H11: barrier/wait convoying capped outstanding-load duty cycle
// at ~27% (the 2 TB/s wall). Fix: waves fully independent, no LDS, no
// barriers in the K-loop; depth-2 register prefetch; compiler-placed waits
// land on loads issued 2 steps earlier.
// Block 512 thr = 8 waves (2 row-halves x 4 col-quarters), 64 rows x 192
// cols per block, grid = 256. Per wave: 32 rows x 48 cols, 10 loads +
// 12 MFMA per K-step, 16 steps.
__global__ __launch_bounds__(512, 2) void gemm_kernel(
        const unsigned short* __restrict__ xb,
        const unsigned short* __restrict__ wtb,
        unsigned short* __restrict__ qb,
        unsigned short* __restrict__ kb,
        unsigned short* __restrict__ vt) {
    __shared__ float vstage[64][65];     // epilogue v transpose only

    const int tid  = threadIdx.x;
    const int lane = tid & 63;
    const int w    = tid >> 6;
    const int l15  = lane & 15;
    const int lg   = lane >> 4;
    const int row0 = blockIdx.x * 64;
    const int rg   = (w >> 2) * 32;      // row half
    const int wc   = (w & 3) * 48;       // col quarter

    // per-lane fragment sources (advance by 64 shorts per step)
    const unsigned short* ap0 = xb + (size_t)(row0 + rg +  0 + l15) * CC + lg * 8;
    const unsigned short* ap1 = xb + (size_t)(row0 + rg + 16 + l15) * CC + lg * 8;
    const unsigned short* bp0 = wtb + (size_t)(wc +  0 + l15) * CC + lg * 8;
    const unsigned short* bp1 = wtb + (size_t)(wc + 16 + l15) * CC + lg * 8;
    const unsigned short* bp2 = wtb + (size_t)(wc + 32 + l15) * CC + lg * 8;

    f32x4 acc[2][3];
    #pragma unroll
    for (int i = 0; i < 2; ++i)
        #pragma unroll
        for (int j = 0; j < 3; ++j)
            acc[i][j] = (f32x4){0.f, 0.f, 0.f, 0.f};

    short8 af[2][2][2];   // [buf][mf][kh]
    short8 bf[2][3][2];   // [buf][nf][kh]

#define KS(s_) (((s_) < 16 ? (s_) : 15) * 64)
#define LOADSTEP(s_, b_) { \
    af[b_][0][0] = *(const short8*)(ap0 + KS(s_));      \
    af[b_][0][1] = *(const short8*)(ap0 + KS(s_) + 32); \
    af[b_][1][0] = *(const short8*)(ap1 + KS(s_));      \
    af[b_][1][1] = *(const short8*)(ap1 + KS(s_) + 32); \
    bf[b_][0][0] = *(const short8*)(bp0 + KS(s_));      \
    bf[b_][0][1] = *(const short8*)(bp0 + KS(s_) + 32); \
    bf[b_][1][0] = *(const short8*)(bp1 + KS(s_));      \
    bf[b_][1][1] = *(const short8*)(bp1 + KS(s_) + 32); \
    bf[b_][2][0] = *(const short8*)(bp2 + KS(s_));      \
    bf[b_][2][1] = *(const short8*)(bp2 + KS(s_) + 32); }

    // prologue: steps 0 and 1 in flight
    LOADSTEP(0, 0);
    LOADSTEP(1, 1);

    #pragma unroll
    for (int t = 0; t < 16; ++t) {
        #pragma unroll
        for (int kh = 0; kh < 2; ++kh)
            #pragma unroll
            for (int nf = 0; nf < 3; ++nf)
                #pragma unroll
                for (int mf = 0; mf < 2; ++mf)
                    acc[mf][nf] = __builtin_amdgcn_mfma_f32_16x16x32_bf16(
                        af[t & 1][mf][kh], bf[t & 1][nf][kh], acc[mf][nf], 0, 0, 0);
        if (t < 14) LOADSTEP(t + 2, t & 1);   // refill the buffer just consumed
    }
#undef KS
#undef LOADSTEP

    // ---- epilogue: q,k direct; v via LDS transpose ----
    const int b = row0 >> 12;
    #pragma unroll
    for (int nf = 0; nf < 3; ++nf) {
        const int ng = wc + nf * 16 + l15;          // output col 0..191
        const int mbase = row0 + rg + lg * 4;
        #pragma unroll
        for (int mf = 0; mf < 2; ++mf) {
            if (ng < 128) {
                unsigned short* dst = (ng < 64) ? qb : kb;
                const int h = ng & 63;
                #pragma unroll
                for (int r = 0; r < 4; ++r)
                    dst[(size_t)(mbase + mf * 16 + r) * HH + h] = f2bf(acc[mf][nf][r]);
            } else {
                #pragma unroll
                for (int r = 0; r < 4; ++r)
                    vstage[ng - 128][rg + mf * 16 + lg * 4 + r] = acc[mf][nf][r];
            }
        }
    }
    __syncthreads();
    {
        const int h  = tid >> 3;           // 0..63
        const int mq = (tid & 7) * 8;      // 0..56
        short8 o;
        #pragma unroll
        for (int j = 0; j < 8; ++j)
            o[j] = (short)f2bf(vstage[h][mq + j]);
        *reinterpret_cast<short8*>(
            vt + ((size_t)(b * 64 + h)) * TT + (row0 & (TT - 1)) + mq) = o;
    }
}

// ---------------- Kernel 2: MFMA windowed causal attention ----------------
// (unchanged since round 4)
__global__ __launch_bounds__(256) void attn_kernel(
        const unsigned short* __restrict__ qb,
        const unsigned short* __restrict__ kb,
        const unsigned short* __restrict__ vt,
        const float* __restrict__ decay,
        float* __restrict__ out) {
    __shared__ unsigned short P[4][16 * 168];

    const int lane = threadIdx.x & 63;
    const int w    = threadIdx.x >> 6;
    const int l15  = lane & 15;
    const int lg   = lane >> 4;
    const int qt   = blockIdx.x * 4 + w;
    const int gb   = qt >> 8;
    const int i0   = (qt & 255) << 4;

    const float dec = fabsf(decay[0]);
    const size_t bbase = (size_t)gb * TT;

    short8 af0, af1;
    {
        const unsigned short* qp = qb + (bbase + i0 + l15) * HH + lg * 8;
        af0 = *(const short8*)(qp);
        af1 = *(const short8*)(qp + 32);
    }

    float psum[4] = {0.f, 0.f, 0.f, 0.f};
    unsigned short* Pw = &P[w][0];

    if (i0 >= 144) {
        const int js = i0 - 144;
        const unsigned short* kp = kb + (bbase + js + l15) * HH + lg * 8;
        #pragma unroll
        for (int ts = 0; ts < 10; ++ts) {
            short8 b0 = *(const short8*)(kp + (size_t)ts * 16 * HH);
            short8 b1 = *(const short8*)(kp + (size_t)ts * 16 * HH + 32);
            f32x4 s = (f32x4){0.f, 0.f, 0.f, 0.f};
            s = __builtin_amdgcn_mfma_f32_16x16x32_bf16(af0, b0, s, 0, 0, 0);
            s = __builtin_amdgcn_mfma_f32_16x16x32_bf16(af1, b1, s, 0, 0, 0);
            const int d0 = 144 + lg * 4 - ts * 16 - l15;
            #pragma unroll
            for (int r = 0; r < 4; ++r) {
                const int d = d0 + r;
                float sv = s[r] * 0.125f - dec * (float)d - 12.0f;
                float p  = (ts == 9 && d < 0) ? 0.0f : __expf(sv);
                psum[r] += p;
                Pw[(lg * 4 + r) * 168 + ts * 16 + l15] = f2bf(p);
            }
        }
        #pragma unroll
        for (int off = 1; off < 16; off <<= 1)
            #pragma unroll
            for (int r = 0; r < 4; ++r)
                psum[r] += __shfl_xor(psum[r], off, 64);

        asm volatile("s_waitcnt lgkmcnt(0)" ::: "memory");
        __builtin_amdgcn_sched_barrier(0);

        f32x4 oacc[4];
        #pragma unroll
        for (int ht = 0; ht < 4; ++ht) oacc[ht] = (f32x4){0.f, 0.f, 0.f, 0.f};
        const unsigned short* vp = vt + ((size_t)(gb * 64) + l15) * TT + js + lg * 8;

        __builtin_amdgcn_s_setprio(1);
        #pragma unroll
        for (int kt = 0; kt < 5; ++kt) {
            short8 pa = *(const short8*)((const char*)Pw + l15 * 336 + kt * 64 + lg * 16);
            #pragma unroll
            for (int ht = 0; ht < 4; ++ht) {
                short8 bv = *(const short8*)(vp + (size_t)ht * 16 * TT + kt * 32);
                oacc[ht] = __builtin_amdgcn_mfma_f32_16x16x32_bf16(pa, bv, oacc[ht], 0, 0, 0);
            }
        }
        __builtin_amdgcn_s_setprio(0);

        float inv[4];
        #pragma unroll
        for (int r = 0; r < 4; ++r) inv[r] = 1.0f / psum[r];
        float* op = out + (bbase + i0 + lg * 4) * HH + l15;
        #pragma unroll
        for (int ht = 0; ht < 4; ++ht)
            #pragma unroll
            for (int r = 0; r < 4; ++r)
                op[(size_t)r * HH + ht * 16] = oacc[ht][r] * inv[r];
    } else {
        const int NS = (i0 >> 4) + 1;
        const int NK = (NS + 1) >> 1;
        const int dbase = i0 + lg * 4 - l15;
        const unsigned short* kp = kb + (bbase + l15) * HH + lg * 8;

        for (int ts = 0; ts < NS; ++ts) {
            short8 b0 = *(const short8*)(kp);
            short8 b1 = *(const short8*)(kp + 32);
            kp += 16 * HH;
            f32x4 s = (f32x4){0.f, 0.f, 0.f, 0.f};
            s = __builtin_amdgcn_mfma_f32_16x16x32_bf16(af0, b0, s, 0, 0, 0);
            s = __builtin_amdgcn_mfma_f32_16x16x32_bf16(af1, b1, s, 0, 0, 0);
            const int d0 = dbase - ts * 16;
            #pragma unroll
            for (int r = 0; r < 4; ++r) {
                const int d = d0 + r;
                float sv = s[r] * 0.125f - dec * (float)d - 12.0f;
                float p  = (d < 0) ? 0.0f : __expf(sv);
                psum[r] += p;
                Pw[(lg * 4 + r) * 168 + ts * 16 + l15] = f2bf(p);
            }
        }
        if (NS & 1) {
            #pragma unroll
            for (int r = 0; r < 4; ++r)
                Pw[(lg * 4 + r) * 168 + NS * 16 + l15] = 0;
        }
        #pragma unroll
        for (int off = 1; off < 16; off <<= 1)
            #pragma unroll
            for (int r = 0; r < 4; ++r)
                psum[r] += __shfl_xor(psum[r], off, 64);

        asm volatile("s_waitcnt lgkmcnt(0)" ::: "memory");
        __builtin_amdgcn_sched_barrier(0);

        f32x4 oacc[4];
        #pragma unroll
        for (int ht = 0; ht < 4; ++ht) oacc[ht] = (f32x4){0.f, 0.f, 0.f, 0.f};
        const unsigned short* vp = vt + ((size_t)(gb * 64) + l15) * TT + lg * 8;

        for (int kt = 0; kt < NK; ++kt) {
            short8 pa = *(const short8*)((const char*)Pw + l15 * 336 + kt * 64 + lg * 16);
            #pragma unroll
            for (int ht = 0; ht < 4; ++ht) {
                short8 bv = *(const short8*)(vp + (size_t)ht * 16 * TT + kt * 32);
                oacc[ht] = __builtin_amdgcn_mfma_f32_16x16x32_bf16(pa, bv, oacc[ht], 0, 0, 0);
            }
        }

        float inv[4];
        #pragma unroll
        for (int r = 0; r < 4; ++r) inv[r] = 1.0f / psum[r];
        float* op = out + (bbase + i0 + lg * 4) * HH + l15;
        #pragma unroll
        for (int ht = 0; ht < 4; ++ht)
            #pragma unroll
            for (int r = 0; r < 4; ++r)
                op[(size_t)r * HH + ht * 16] = oacc[ht][r] * inv[r];
    }
}

extern "C" void kernel_launch(void* const* d_in, const int* in_sizes, int n_in,
                              void* d_out, int out_size, void* d_ws, size_t ws_size,
                              hipStream_t stream) {
    const float* x     = (const float*)d_in[0];
    const float* Wq    = (const float*)d_in[1];
    const float* Wk    = (const float*)d_in[2];
    const float* Wv    = (const float*)d_in[3];
    const float* decay = (const float*)d_in[4];
    float* out = (float*)d_out;

    unsigned short* qb  = (unsigned short*)d_ws;          // 2 MB
    unsigned short* kb  = qb + (size_t)MM * HH;           // 2 MB
    unsigned short* vt  = kb + (size_t)MM * HH;           // 2 MB (transposed)
    unsigned short* wtb = vt + (size_t)MM * HH;           // 384 KB
    unsigned short* xb  = wtb + (size_t)192 * CC;         // 32 MB bf16 x

    convw_kernel<<<48, 256, 0, stream>>>(Wq, Wk, Wv, wtb);
    xconv_kernel<<<MM * CC / 2048, 256, 0, stream>>>(x, xb);
    gemm_kernel<<<MM / 64, 512, 0, stream>>>(xb, wtb, qb, kb, vt);
    attn_kernel<<<MM / 64, 256, 0, stream>>>(qb, kb, vt, decay, out);
}

// Round 12
// 35.845 us; speedup vs baseline: 1.9832x; 1.9832x over previous
//
#include <hip/hip_runtime.h>
#include <math.h>

#define BB 4
#define TT 4096
#define CC 1024
#define HH 64
#define MM (BB*TT)

typedef __attribute__((ext_vector_type(8))) short  short8;
typedef __attribute__((ext_vector_type(4))) short  short4v;
typedef __attribute__((ext_vector_type(4))) float  f32x4;

typedef const __attribute__((address_space(1))) unsigned int GU;
typedef __attribute__((address_space(3))) unsigned int LU;

static __device__ __forceinline__ unsigned short f2bf(float f) {
    union { float f; unsigned u; } v; v.f = f;
    unsigned r = v.u + 0x7FFF + ((v.u >> 16) & 1);
    return (unsigned short)(r >> 16);
}

// 8x fp32 -> 8x bf16 (RNE) via v_cvt_pk_bf16_f32
static __device__ __forceinline__ short8 cvt8(float4 lo, float4 hi) {
    unsigned u0, u1, u2, u3;
    asm("v_cvt_pk_bf16_f32 %0, %1, %2" : "=v"(u0) : "v"(lo.x), "v"(lo.y));
    asm("v_cvt_pk_bf16_f32 %0, %1, %2" : "=v"(u1) : "v"(lo.z), "v"(lo.w));
    asm("v_cvt_pk_bf16_f32 %0, %1, %2" : "=v"(u2) : "v"(hi.x), "v"(hi.y));
    asm("v_cvt_pk_bf16_f32 %0, %1, %2" : "=v"(u3) : "v"(hi.z), "v"(hi.w));
    union { unsigned u[4]; short8 s; } r;
    r.u[0] = u0; r.u[1] = u1; r.u[2] = u2; r.u[3] = u3;
    return r.s;
}

// ---------------- Kernel 0: W -> W^T bf16 (tiny, unchanged) ----------------
__global__ __launch_bounds__(256) void convw_kernel(
        const float* __restrict__ Wq, const float* __restrict__ Wk,
        const float* __restrict__ Wv, unsigned short* __restrict__ wtb) {
    __shared__ unsigned short sW[64][66];
    const int m    = blockIdx.x >> 4;
    const int cblk = blockIdx.x & 15;
    const float* W = (m == 0) ? Wq : (m == 1) ? Wk : Wv;
    const int lane = threadIdx.x & 63;
    const int w    = threadIdx.x >> 6;
    #pragma unroll
    for (int rep = 0; rep < 16; ++rep) {
        const int cl = w * 16 + rep;
        sW[cl][lane] = f2bf(W[(size_t)(cblk * 64 + cl) * HH + lane]);
    }
    __syncthreads();
    #pragma unroll
    for (int rep = 0; rep < 16; ++rep) {
        const int h2 = w * 16 + rep;
        wtb[(size_t)(m * 64 + h2) * CC + cblk * 64 + lane] = sW[lane][h2];
    }
}

// ---------------- Kernel 1: r4 base + m201-style counted-vmcnt pipeline ----
// BM=32, BN=192, BK=64, grid=512, 256 thr = 4 waves (2 rg x 2 cg of 96).
// B: 3x24KB LDS ring via global_load_lds, issued 2 steps ahead;
//    per-iter wait = vmcnt(16) (both future steps stay in flight).
// A: fp32 global->reg (3-slot ring, 2 ahead) -> cvt_pk -> single 4KB LDS buf.
// Minimal fencing: one sched_barrier before the waitcnt pair, lgkm fence
// before barrier #1 (rule #18). LDS 76KB -> 2 blocks/CU.
__global__ __launch_bounds__(256, 2) void gemm_kernel(
        const float* __restrict__ x,
        const unsigned short* __restrict__ wtb,
        unsigned short* __restrict__ qb,
        unsigned short* __restrict__ kb,
        unsigned short* __restrict__ vt) {
    __shared__ unsigned short As[32 * 64];       // 4 KB, single buffer
    __shared__ unsigned short Bs[3][192 * 64];   // 3 x 24 KB ring

    const int tid  = threadIdx.x;
    const int lane = tid & 63;
    const int w    = tid >> 6;
    const int l15  = lane & 15;
    const int lg   = lane >> 4;
    const int row0 = blockIdx.x * 32;
    const int rg   = (w >> 1) * 16;     // row group: 0 or 16
    const int wc   = (w & 1) * 96;      // col group: 0 or 96

    f32x4 acc[6];
    #pragma unroll
    for (int j = 0; j < 6; ++j) acc[j] = (f32x4){0.f, 0.f, 0.f, 0.f};

    // A staging map (r4-verified): thread -> row ar = tid>>3, octet akq = tid&7
    const int ar  = tid >> 3;
    const int akq = tid & 7;
    const float* xrow = x + (size_t)(row0 + ar) * CC + akq * 8;
    char* adst = (char*)As + ar * 128 + ((akq ^ (ar & 7)) * 16);

    float4 araw[3][2];

#define STAGE_B(s_, bufi_) { \
    const int kc_ = (s_) * 64; \
    _Pragma("unroll") \
    for (int it = 0; it < 6; ++it) { \
        const int lidx = it * 4096 + tid * 16; \
        const int r_  = lidx >> 7; \
        const int cb_ = (((lidx & 127) >> 4) ^ (r_ & 7)); \
        __builtin_amdgcn_global_load_lds( \
            (GU*)(wtb + (size_t)r_ * CC + kc_ + cb_ * 8), \
            (LU*)((char*)Bs[bufi_] + it * 4096 + w * 1024), 16, 0, 0); \
    } }
#define LOAD_A(s_, sl_) { \
    const int kc_ = (s_) * 64; \
    araw[sl_][0] = *(const float4*)(xrow + kc_); \
    araw[sl_][1] = *(const float4*)(xrow + kc_ + 4); }

    // ---- prologue: 2 steps in flight (16 VMEM instrs/thread) ----
    STAGE_B(0, 0); LOAD_A(0, 0);
    STAGE_B(1, 1); LOAD_A(1, 1);

    const int swz = (l15 & 7) << 4;

    #pragma unroll
    for (int t = 0; t < 16; ++t) {
        if (t < 14) { STAGE_B(t + 2, (t + 2) % 3); LOAD_A(t + 2, (t + 2) % 3); }
        __builtin_amdgcn_sched_barrier(0);
        if (t < 14)       { asm volatile("s_waitcnt vmcnt(16)" ::: "memory"); }
        else if (t == 14) { asm volatile("s_waitcnt vmcnt(8)"  ::: "memory"); }
        else              { asm volatile("s_waitcnt vmcnt(0)"  ::: "memory"); }

        // cvt + ds_write A(t)
        short8 av = cvt8(araw[t % 3][0], araw[t % 3][1]);
        *reinterpret_cast<short8*>(adst) = av;
        asm volatile("s_waitcnt lgkmcnt(0)" ::: "memory");
        __builtin_amdgcn_sched_barrier(0);
        __builtin_amdgcn_s_barrier();        // #1: B(t) + A(t) visible

        const char* Asc = (const char*)As;
        const char* Bsc = (const char*)Bs[t % 3];
        short8 af[2];
        #pragma unroll
        for (int kh = 0; kh < 2; ++kh)
            af[kh] = *(const short8*)(Asc + (rg + l15) * 128 + ((kh * 64 + lg * 16) ^ swz));
        short8 bf[6][2];
        #pragma unroll
        for (int nf = 0; nf < 6; ++nf)
            #pragma unroll
            for (int kh = 0; kh < 2; ++kh) {
                const int n = wc + nf * 16 + l15;
                bf[nf][kh] = *(const short8*)(Bsc + n * 128 + ((kh * 64 + lg * 16) ^ swz));
            }
        __builtin_amdgcn_s_setprio(1);
        #pragma unroll
        for (int kh = 0; kh < 2; ++kh)
            #pragma unroll
            for (int nf = 0; nf < 6; ++nf)
                acc[nf] = __builtin_amdgcn_mfma_f32_16x16x32_bf16(
                    af[kh], bf[nf][kh], acc[nf], 0, 0, 0);
        __builtin_amdgcn_s_setprio(0);

        __builtin_amdgcn_s_barrier();        // #2: release Bs[t%3], As
        __builtin_amdgcn_sched_barrier(0);
    }
#undef STAGE_B
#undef LOAD_A

    // ---- epilogue (r4-verbatim): q,k row-major bf16; v transposed ----
    const int b = row0 >> 12;
    #pragma unroll
    for (int nf = 0; nf < 6; ++nf) {
        const int ng = wc + nf * 16 + l15;
        const int m  = ng >> 6, h = ng & 63;
        const int rowbase = row0 + rg + lg * 4;
        if (m == 2) {
            short4v pk;
            pk[0] = (short)f2bf(acc[nf][0]);
            pk[1] = (short)f2bf(acc[nf][1]);
            pk[2] = (short)f2bf(acc[nf][2]);
            pk[3] = (short)f2bf(acc[nf][3]);
            *reinterpret_cast<short4v*>(
                &vt[((size_t)(b * 64 + h)) * TT + (rowbase & (TT - 1))]) = pk;
        } else {
            unsigned short* dst = (m == 0) ? qb : kb;
            #pragma unroll
            for (int r = 0; r < 4; ++r)
                dst[(size_t)(rowbase + r) * HH + h] = f2bf(acc[nf][r]);
        }
    }
}

// ---------------- Kernel 2: MFMA windowed causal attention ----------------
// (unchanged since round 4)
__global__ __launch_bounds__(256) void attn_kernel(
        const unsigned short* __restrict__ qb,
        const unsigned short* __restrict__ kb,
        const unsigned short* __restrict__ vt,
        const float* __restrict__ decay,
        float* __restrict__ out) {
    __shared__ unsigned short P[4][16 * 168];

    const int lane = threadIdx.x & 63;
    const int w    = threadIdx.x >> 6;
    const int l15  = lane & 15;
    const int lg   = lane >> 4;
    const int qt   = blockIdx.x * 4 + w;
    const int gb   = qt >> 8;
    const int i0   = (qt & 255) << 4;

    const float dec = fabsf(decay[0]);
    const size_t bbase = (size_t)gb * TT;

    short8 af0, af1;
    {
        const unsigned short* qp = qb + (bbase + i0 + l15) * HH + lg * 8;
        af0 = *(const short8*)(qp);
        af1 = *(const short8*)(qp + 32);
    }

    float psum[4] = {0.f, 0.f, 0.f, 0.f};
    unsigned short* Pw = &P[w][0];

    if (i0 >= 144) {
        const int js = i0 - 144;
        const unsigned short* kp = kb + (bbase + js + l15) * HH + lg * 8;
        #pragma unroll
        for (int ts = 0; ts < 10; ++ts) {
            short8 b0 = *(const short8*)(kp + (size_t)ts * 16 * HH);
            short8 b1 = *(const short8*)(kp + (size_t)ts * 16 * HH + 32);
            f32x4 s = (f32x4){0.f, 0.f, 0.f, 0.f};
            s = __builtin_amdgcn_mfma_f32_16x16x32_bf16(af0, b0, s, 0, 0, 0);
            s = __builtin_amdgcn_mfma_f32_16x16x32_bf16(af1, b1, s, 0, 0, 0);
            const int d0 = 144 + lg * 4 - ts * 16 - l15;
            #pragma unroll
            for (int r = 0; r < 4; ++r) {
                const int d = d0 + r;
                float sv = s[r] * 0.125f - dec * (float)d - 12.0f;
                float p  = (ts == 9 && d < 0) ? 0.0f : __expf(sv);
                psum[r] += p;
                Pw[(lg * 4 + r) * 168 + ts * 16 + l15] = f2bf(p);
            }
        }
        #pragma unroll
        for (int off = 1; off < 16; off <<= 1)
            #pragma unroll
            for (int r = 0; r < 4; ++r)
                psum[r] += __shfl_xor(psum[r], off, 64);

        asm volatile("s_waitcnt lgkmcnt(0)" ::: "memory");
        __builtin_amdgcn_sched_barrier(0);

        f32x4 oacc[4];
        #pragma unroll
        for (int ht = 0; ht < 4; ++ht) oacc[ht] = (f32x4){0.f, 0.f, 0.f, 0.f};
        const unsigned short* vp = vt + ((size_t)(gb * 64) + l15) * TT + js + lg * 8;

        __builtin_amdgcn_s_setprio(1);
        #pragma unroll
        for (int kt = 0; kt < 5; ++kt) {
            short8 pa = *(const short8*)((const char*)Pw + l15 * 336 + kt * 64 + lg * 16);
            #pragma unroll
            for (int ht = 0; ht < 4; ++ht) {
                short8 bv = *(const short8*)(vp + (size_t)ht * 16 * TT + kt * 32);
                oacc[ht] = __builtin_amdgcn_mfma_f32_16x16x32_bf16(pa, bv, oacc[ht], 0, 0, 0);
            }
        }
        __builtin_amdgcn_s_setprio(0);

        float inv[4];
        #pragma unroll
        for (int r = 0; r < 4; ++r) inv[r] = 1.0f / psum[r];
        float* op = out + (bbase + i0 + lg * 4) * HH + l15;
        #pragma unroll
        for (int ht = 0; ht < 4; ++ht)
            #pragma unroll
            for (int r = 0; r < 4; ++r)
                op[(size_t)r * HH + ht * 16] = oacc[ht][r] * inv[r];
    } else {
        const int NS = (i0 >> 4) + 1;
        const int NK = (NS + 1) >> 1;
        const int dbase = i0 + lg * 4 - l15;
        const unsigned short* kp = kb + (bbase + l15) * HH + lg * 8;

        for (int ts = 0; ts < NS; ++ts) {
            short8 b0 = *(const short8*)(kp);
            short8 b1 = *(const short8*)(kp + 32);
            kp += 16 * HH;
            f32x4 s = (f32x4){0.f, 0.f, 0.f, 0.f};
            s = __builtin_amdgcn_mfma_f32_16x16x32_bf16(af0, b0, s, 0, 0, 0);
            s = __builtin_amdgcn_mfma_f32_16x16x32_bf16(af1, b1, s, 0, 0, 0);
            const int d0 = dbase - ts * 16;
            #pragma unroll
            for (int r = 0; r < 4; ++r) {
                const int d = d0 + r;
                float sv = s[r] * 0.125f - dec * (float)d - 12.0f;
                float p  = (d < 0) ? 0.0f : __expf(sv);
                psum[r] += p;
                Pw[(lg * 4 + r) * 168 + ts * 16 + l15] = f2bf(p);
            }
        }
        if (NS & 1) {
            #pragma unroll
            for (int r = 0; r < 4; ++r)
                Pw[(lg * 4 + r) * 168 + NS * 16 + l15] = 0;
        }
        #pragma unroll
        for (int off = 1; off < 16; off <<= 1)
            #pragma unroll
            for (int r = 0; r < 4; ++r)
                psum[r] += __shfl_xor(psum[r], off, 64);

        asm volatile("s_waitcnt lgkmcnt(0)" ::: "memory");
        __builtin_amdgcn_sched_barrier(0);

        f32x4 oacc[4];
        #pragma unroll
        for (int ht = 0; ht < 4; ++ht) oacc[ht] = (f32x4){0.f, 0.f, 0.f, 0.f};
        const unsigned short* vp = vt + ((size_t)(gb * 64) + l15) * TT + lg * 8;

        for (int kt = 0; kt < NK; ++kt) {
            short8 pa = *(const short8*)((const char*)Pw + l15 * 336 + kt * 64 + lg * 16);
            #pragma unroll
            for (int ht = 0; ht < 4; ++ht) {
                short8 bv = *(const short8*)(vp + (size_t)ht * 16 * TT + kt * 32);
                oacc[ht] = __builtin_amdgcn_mfma_f32_16x16x32_bf16(pa, bv, oacc[ht], 0, 0, 0);
            }
        }

        float inv[4];
        #pragma unroll
        for (int r = 0; r < 4; ++r) inv[r] = 1.0f / psum[r];
        float* op = out + (bbase + i0 + lg * 4) * HH + l15;
        #pragma unroll
        for (int ht = 0; ht < 4; ++ht)
            #pragma unroll
            for (int r = 0; r < 4; ++r)
                op[(size_t)r * HH + ht * 16] = oacc[ht][r] * inv[r];
    }
}

extern "C" void kernel_launch(void* const* d_in, const int* in_sizes, int n_in,
                              void* d_out, int out_size, void* d_ws, size_t ws_size,
                              hipStream_t stream) {
    const float* x     = (const float*)d_in[0];
    const float* Wq    = (const float*)d_in[1];
    const float* Wk    = (const float*)d_in[2];
    const float* Wv    = (const float*)d_in[3];
    const float* decay = (const float*)d_in[4];
    float* out = (float*)d_out;

    unsigned short* qb  = (unsigned short*)d_ws;          // 2 MB
    unsigned short* kb  = qb + (size_t)MM * HH;           // 2 MB
    unsigned short* vt  = kb + (size_t)MM * HH;           // 2 MB (transposed)
    unsigned short* wtb = vt + (size_t)MM * HH;           // 384 KB

    convw_kernel<<<48, 256, 0, stream>>>(Wq, Wk, Wv, wtb);
    gemm_kernel<<<MM / 32, 256, 0, stream>>>(x, wtb, qb, kb, vt);
    attn_kernel<<<MM / 64, 256, 0, stream>>>(qb, kb, vt, decay, out);
}

// Round 13
// 34.836 us; speedup vs baseline: 2.0406x; 1.0290x over previous
//
#include <hip/hip_runtime.h>
#include <math.h>

#define BB 4
#define TT 4096
#define CC 1024
#define HH 64
#define MM (BB*TT)

typedef __attribute__((ext_vector_type(8))) short  short8;
typedef __attribute__((ext_vector_type(4))) short  short4v;
typedef __attribute__((ext_vector_type(4))) float  f32x4;

typedef const __attribute__((address_space(1))) unsigned int GU;
typedef __attribute__((address_space(3))) unsigned int LU;

static __device__ __forceinline__ unsigned short f2bf(float f) {
    union { float f; unsigned u; } v; v.f = f;
    unsigned r = v.u + 0x7FFF + ((v.u >> 16) & 1);
    return (unsigned short)(r >> 16);
}

// 4x fp32 -> 4x bf16 (RNE) via v_cvt_pk_bf16_f32
static __device__ __forceinline__ short4v cvt4(float4 a) {
    unsigned u0, u1;
    asm("v_cvt_pk_bf16_f32 %0, %1, %2" : "=v"(u0) : "v"(a.x), "v"(a.y));
    asm("v_cvt_pk_bf16_f32 %0, %1, %2" : "=v"(u1) : "v"(a.z), "v"(a.w));
    union { unsigned u[2]; short4v s; } r;
    r.u[0] = u0; r.u[1] = u1;
    return r.s;
}

// ---------------- Kernel 0: W -> W^T bf16 (tiny, unchanged) ----------------
__global__ __launch_bounds__(256) void convw_kernel(
        const float* __restrict__ Wq, const float* __restrict__ Wk,
        const float* __restrict__ Wv, unsigned short* __restrict__ wtb) {
    __shared__ unsigned short sW[64][66];
    const int m    = blockIdx.x >> 4;
    const int cblk = blockIdx.x & 15;
    const float* W = (m == 0) ? Wq : (m == 1) ? Wk : Wv;
    const int lane = threadIdx.x & 63;
    const int w    = threadIdx.x >> 6;
    #pragma unroll
    for (int rep = 0; rep < 16; ++rep) {
        const int cl = w * 16 + rep;
        sW[cl][lane] = f2bf(W[(size_t)(cblk * 64 + cl) * HH + lane]);
    }
    __syncthreads();
    #pragma unroll
    for (int rep = 0; rep < 16; ++rep) {
        const int h2 = w * 16 + rep;
        wtb[(size_t)(m * 64 + h2) * CC + cblk * 64 + lane] = sW[lane][h2];
    }
}

// ---------------- Kernel 1: r12 pipeline, 8 waves (TLP x2) -----------------
// BM=32, BN=192, BK=64, grid=512, 512 thr = 8 waves (2 rg x 4 cg of 48).
// B: 3x24KB LDS ring via global_load_lds, 2 steps ahead; wait vmcnt(8).
// A: fp32 global->reg (3-slot ring) -> cvt_pk -> single 4KB LDS buffer.
// LDS 76KB -> 2 blocks/CU = 4 waves/SIMD (2x r12's TLP; barrier stalls of
// one wave overlap compute of the other three).
__global__ __launch_bounds__(512, 2) void gemm_kernel(
        const float* __restrict__ x,
        const unsigned short* __restrict__ wtb,
        unsigned short* __restrict__ qb,
        unsigned short* __restrict__ kb,
        unsigned short* __restrict__ vt) {
    __shared__ unsigned short As[32 * 64];       // 4 KB, single buffer
    __shared__ unsigned short Bs[3][192 * 64];   // 3 x 24 KB ring

    const int tid  = threadIdx.x;
    const int lane = tid & 63;
    const int w    = tid >> 6;
    const int l15  = lane & 15;
    const int lg   = lane >> 4;
    const int row0 = blockIdx.x * 32;
    const int rg   = (w >> 2) * 16;     // row group: 0 or 16
    const int wc   = (w & 3) * 48;      // col group base

    f32x4 acc[3];
    #pragma unroll
    for (int j = 0; j < 3; ++j) acc[j] = (f32x4){0.f, 0.f, 0.f, 0.f};

    // A staging map: thread -> row ar = tid>>4, octet akq = (tid&15)>>1, half
    const int ar   = tid >> 4;            // 0..31
    const int akq  = (tid & 15) >> 1;     // 0..7
    const int half = tid & 1;
    const float* xrow = x + (size_t)(row0 + ar) * CC + akq * 8 + half * 4;
    char* adst = (char*)As + ar * 128 + ((akq ^ (ar & 7)) * 16) + half * 8;

    float4 araw[3];

#define STAGE_B(s_, bufi_) { \
    const int kc_ = (s_) * 64; \
    _Pragma("unroll") \
    for (int it = 0; it < 3; ++it) { \
        const int lidx = it * 8192 + tid * 16; \
        const int r_  = lidx >> 7; \
        const int cb_ = (((lidx & 127) >> 4) ^ (r_ & 7)); \
        __builtin_amdgcn_global_load_lds( \
            (GU*)(wtb + (size_t)r_ * CC + kc_ + cb_ * 8), \
            (LU*)((char*)Bs[bufi_] + it * 8192 + w * 1024), 16, 0, 0); \
    } }
#define LOAD_A(s_, sl_) { \
    araw[sl_] = *(const float4*)(xrow + (s_) * 64); }

    // ---- prologue: 2 steps in flight (8 VMEM instrs/thread) ----
    STAGE_B(0, 0); LOAD_A(0, 0);
    STAGE_B(1, 1); LOAD_A(1, 1);

    const int swz = (l15 & 7) << 4;

    #pragma unroll
    for (int t = 0; t < 16; ++t) {
        if (t < 14) { STAGE_B(t + 2, (t + 2) % 3); LOAD_A(t + 2, (t + 2) % 3); }
        __builtin_amdgcn_sched_barrier(0);
        if (t < 14)       { asm volatile("s_waitcnt vmcnt(8)" ::: "memory"); }
        else if (t == 14) { asm volatile("s_waitcnt vmcnt(4)" ::: "memory"); }
        else              { asm volatile("s_waitcnt vmcnt(0)" ::: "memory"); }

        // cvt + ds_write A(t)
        short4v av = cvt4(araw[t % 3]);
        *reinterpret_cast<short4v*>(adst) = av;
        asm volatile("s_waitcnt lgkmcnt(0)" ::: "memory");
        __builtin_amdgcn_sched_barrier(0);
        __builtin_amdgcn_s_barrier();        // #1: B(t) + A(t) visible

        const char* Asc = (const char*)As;
        const char* Bsc = (const char*)Bs[t % 3];
        short8 af[2];
        #pragma unroll
        for (int kh = 0; kh < 2; ++kh)
            af[kh] = *(const short8*)(Asc + (rg + l15) * 128 + ((kh * 64 + lg * 16) ^ swz));
        short8 bf[3][2];
        #pragma unroll
        for (int nf = 0; nf < 3; ++nf)
            #pragma unroll
            for (int kh = 0; kh < 2; ++kh) {
                const int n = wc + nf * 16 + l15;
                bf[nf][kh] = *(const short8*)(Bsc + n * 128 + ((kh * 64 + lg * 16) ^ swz));
            }
        __builtin_amdgcn_s_setprio(1);
        #pragma unroll
        for (int kh = 0; kh < 2; ++kh)
            #pragma unroll
            for (int nf = 0; nf < 3; ++nf)
                acc[nf] = __builtin_amdgcn_mfma_f32_16x16x32_bf16(
                    af[kh], bf[nf][kh], acc[nf], 0, 0, 0);
        __builtin_amdgcn_s_setprio(0);

        __builtin_amdgcn_s_barrier();        // #2: release Bs[t%3], As
        __builtin_amdgcn_sched_barrier(0);
    }
#undef STAGE_B
#undef LOAD_A

    // ---- epilogue: q,k row-major bf16; v transposed vt[b][h][t] ----
    const int b = row0 >> 12;
    #pragma unroll
    for (int nf = 0; nf < 3; ++nf) {
        const int ng = wc + nf * 16 + l15;
        const int m  = ng >> 6, h = ng & 63;
        const int rowbase = row0 + rg + lg * 4;
        if (m == 2) {
            short4v pk;
            pk[0] = (short)f2bf(acc[nf][0]);
            pk[1] = (short)f2bf(acc[nf][1]);
            pk[2] = (short)f2bf(acc[nf][2]);
            pk[3] = (short)f2bf(acc[nf][3]);
            *reinterpret_cast<short4v*>(
                &vt[((size_t)(b * 64 + h)) * TT + (rowbase & (TT - 1))]) = pk;
        } else {
            unsigned short* dst = (m == 0) ? qb : kb;
            #pragma unroll
            for (int r = 0; r < 4; ++r)
                dst[(size_t)(rowbase + r) * HH + h] = f2bf(acc[nf][r]);
        }
    }
}

// ---------------- Kernel 2: MFMA windowed causal attention ----------------
// (unchanged since round 4)
__global__ __launch_bounds__(256) void attn_kernel(
        const unsigned short* __restrict__ qb,
        const unsigned short* __restrict__ kb,
        const unsigned short* __restrict__ vt,
        const float* __restrict__ decay,
        float* __restrict__ out) {
    __shared__ unsigned short P[4][16 * 168];

    const int lane = threadIdx.x & 63;
    const int w    = threadIdx.x >> 6;
    const int l15  = lane & 15;
    const int lg   = lane >> 4;
    const int qt   = blockIdx.x * 4 + w;
    const int gb   = qt >> 8;
    const int i0   = (qt & 255) << 4;

    const float dec = fabsf(decay[0]);
    const size_t bbase = (size_t)gb * TT;

    short8 af0, af1;
    {
        const unsigned short* qp = qb + (bbase + i0 + l15) * HH + lg * 8;
        af0 = *(const short8*)(qp);
        af1 = *(const short8*)(qp + 32);
    }

    float psum[4] = {0.f, 0.f, 0.f, 0.f};
    unsigned short* Pw = &P[w][0];

    if (i0 >= 144) {
        const int js = i0 - 144;
        const unsigned short* kp = kb + (bbase + js + l15) * HH + lg * 8;
        #pragma unroll
        for (int ts = 0; ts < 10; ++ts) {
            short8 b0 = *(const short8*)(kp + (size_t)ts * 16 * HH);
            short8 b1 = *(const short8*)(kp + (size_t)ts * 16 * HH + 32);
            f32x4 s = (f32x4){0.f, 0.f, 0.f, 0.f};
            s = __builtin_amdgcn_mfma_f32_16x16x32_bf16(af0, b0, s, 0, 0, 0);
            s = __builtin_amdgcn_mfma_f32_16x16x32_bf16(af1, b1, s, 0, 0, 0);
            const int d0 = 144 + lg * 4 - ts * 16 - l15;
            #pragma unroll
            for (int r = 0; r < 4; ++r) {
                const int d = d0 + r;
                float sv = s[r] * 0.125f - dec * (float)d - 12.0f;
                float p  = (ts == 9 && d < 0) ? 0.0f : __expf(sv);
                psum[r] += p;
                Pw[(lg * 4 + r) * 168 + ts * 16 + l15] = f2bf(p);
            }
        }
        #pragma unroll
        for (int off = 1; off < 16; off <<= 1)
            #pragma unroll
            for (int r = 0; r < 4; ++r)
                psum[r] += __shfl_xor(psum[r], off, 64);

        asm volatile("s_waitcnt lgkmcnt(0)" ::: "memory");
        __builtin_amdgcn_sched_barrier(0);

        f32x4 oacc[4];
        #pragma unroll
        for (int ht = 0; ht < 4; ++ht) oacc[ht] = (f32x4){0.f, 0.f, 0.f, 0.f};
        const unsigned short* vp = vt + ((size_t)(gb * 64) + l15) * TT + js + lg * 8;

        __builtin_amdgcn_s_setprio(1);
        #pragma unroll
        for (int kt = 0; kt < 5; ++kt) {
            short8 pa = *(const short8*)((const char*)Pw + l15 * 336 + kt * 64 + lg * 16);
            #pragma unroll
            for (int ht = 0; ht < 4; ++ht) {
                short8 bv = *(const short8*)(vp + (size_t)ht * 16 * TT + kt * 32);
                oacc[ht] = __builtin_amdgcn_mfma_f32_16x16x32_bf16(pa, bv, oacc[ht], 0, 0, 0);
            }
        }
        __builtin_amdgcn_s_setprio(0);

        float inv[4];
        #pragma unroll
        for (int r = 0; r < 4; ++r) inv[r] = 1.0f / psum[r];
        float* op = out + (bbase + i0 + lg * 4) * HH + l15;
        #pragma unroll
        for (int ht = 0; ht < 4; ++ht)
            #pragma unroll
            for (int r = 0; r < 4; ++r)
                op[(size_t)r * HH + ht * 16] = oacc[ht][r] * inv[r];
    } else {
        const int NS = (i0 >> 4) + 1;
        const int NK = (NS + 1) >> 1;
        const int dbase = i0 + lg * 4 - l15;
        const unsigned short* kp = kb + (bbase + l15) * HH + lg * 8;

        for (int ts = 0; ts < NS; ++ts) {
            short8 b0 = *(const short8*)(kp);
            short8 b1 = *(const short8*)(kp + 32);
            kp += 16 * HH;
            f32x4 s = (f32x4){0.f, 0.f, 0.f, 0.f};
            s = __builtin_amdgcn_mfma_f32_16x16x32_bf16(af0, b0, s, 0, 0, 0);
            s = __builtin_amdgcn_mfma_f32_16x16x32_bf16(af1, b1, s, 0, 0, 0);
            const int d0 = dbase - ts * 16;
            #pragma unroll
            for (int r = 0; r < 4; ++r) {
                const int d = d0 + r;
                float sv = s[r] * 0.125f - dec * (float)d - 12.0f;
                float p  = (d < 0) ? 0.0f : __expf(sv);
                psum[r] += p;
                Pw[(lg * 4 + r) * 168 + ts * 16 + l15] = f2bf(p);
            }
        }
        if (NS & 1) {
            #pragma unroll
            for (int r = 0; r < 4; ++r)
                Pw[(lg * 4 + r) * 168 + NS * 16 + l15] = 0;
        }
        #pragma unroll
        for (int off = 1; off < 16; off <<= 1)
            #pragma unroll
            for (int r = 0; r < 4; ++r)
                psum[r] += __shfl_xor(psum[r], off, 64);

        asm volatile("s_waitcnt lgkmcnt(0)" ::: "memory");
        __builtin_amdgcn_sched_barrier(0);

        f32x4 oacc[4];
        #pragma unroll
        for (int ht = 0; ht < 4; ++ht) oacc[ht] = (f32x4){0.f, 0.f, 0.f, 0.f};
        const unsigned short* vp = vt + ((size_t)(gb * 64) + l15) * TT + lg * 8;

        for (int kt = 0; kt < NK; ++kt) {
            short8 pa = *(const short8*)((const char*)Pw + l15 * 336 + kt * 64 + lg * 16);
            #pragma unroll
            for (int ht = 0; ht < 4; ++ht) {
                short8 bv = *(const short8*)(vp + (size_t)ht * 16 * TT + kt * 32);
                oacc[ht] = __builtin_amdgcn_mfma_f32_16x16x32_bf16(pa, bv, oacc[ht], 0, 0, 0);
            }
        }

        float inv[4];
        #pragma unroll
        for (int r = 0; r < 4; ++r) inv[r] = 1.0f / psum[r];
        float* op = out + (bbase + i0 + lg * 4) * HH + l15;
        #pragma unroll
        for (int ht = 0; ht < 4; ++ht)
            #pragma unroll
            for (int r = 0; r < 4; ++r)
                op[(size_t)r * HH + ht * 16] = oacc[ht][r] * inv[r];
    }
}

extern "C" void kernel_launch(void* const* d_in, const int* in_sizes, int n_in,
                              void* d_out, int out_size, void* d_ws, size_t ws_size,
                              hipStream_t stream) {
    const float* x     = (const float*)d_in[0];
    const float* Wq    = (const float*)d_in[1];
    const float* Wk    = (const float*)d_in[2];
    const float* Wv    = (const float*)d_in[3];
    const float* decay = (const float*)d_in[4];
    float* out = (float*)d_out;

    unsigned short* qb  = (unsigned short*)d_ws;          // 2 MB
    unsigned short* kb  = qb + (size_t)MM * HH;           // 2 MB
    unsigned short* vt  = kb + (size_t)MM * HH;           // 2 MB (transposed)
    unsigned short* wtb = vt + (size_t)MM * HH;           // 384 KB

    convw_kernel<<<48, 256, 0, stream>>>(Wq, Wk, Wv, wtb);
    gemm_kernel<<<MM / 32, 512, 0, stream>>>(x, wtb, qb, kb, vt);
    attn_kernel<<<MM / 64, 256, 0, stream>>>(qb, kb, vt, decay, out);
}